// Round 12
// baseline (167.400 us; speedup 1.0000x reference)
//
#include <hip/hip_runtime.h>
#include <hip/hip_bf16.h>

#define D_R 128
#define D_H 96
#define D_IN 224   // D_R + D_H
#define D_OUT 96
#define CAP 64     // bucket slots per node (256B rows, line-aligned); P(deg>=64) ~ 1e-38
#define NW 21504   // D_OUT * D_IN
#define WPAD 232   // padded W row stride in bf16 (464B: 2-way LDS alias only)

typedef __attribute__((ext_vector_type(8))) short short8;
typedef __attribute__((ext_vector_type(4))) float f32x4;

static __device__ inline unsigned short f2b(float x) {
    __hip_bfloat16 b = __float2bfloat16(x);
    unsigned short u;
    __builtin_memcpy(&u, &b, 2);
    return u;
}

// -------- init: zero deg + convert W fp32->bf16 (one kernel, two ranges) ----
__global__ __launch_bounds__(256) void init_kernel(
    int* __restrict__ deg, int n_nodes,
    const float* __restrict__ W, unsigned short* __restrict__ W16)
{
    int i = blockIdx.x * 256 + threadIdx.x;
    if (i < n_nodes) deg[i] = 0;
    if (i < NW) W16[i] = f2b(W[i]);
}

// -------- single-pass bucket build (count+alloc+fill merged) ----------------
// Bucket scatter stores are NONTEMPORAL: 4B writes to random 256B rows would
// otherwise pay a 128B line fetch + writeback (write-allocate RMW) each --
// ~200MB of hidden traffic for 800K edges.
__global__ __launch_bounds__(256) void build_kernel(
    const int* __restrict__ nbrs, int* __restrict__ deg,
    int* __restrict__ bucket, int n_edges)
{
    int k = blockIdx.x * 256 + threadIdx.x;
    int e0 = 2 * k;
    if (e0 >= n_edges) return;
    if (e0 + 1 < n_edges) {
        int4 q = *reinterpret_cast<const int4*>(nbrs + 2 * e0);
        int p0 = atomicAdd(&deg[q.x], 1);
        if (p0 < CAP)
            __builtin_nontemporal_store(e0, &bucket[(size_t)q.x * CAP + p0]);
        int p1 = atomicAdd(&deg[q.z], 1);
        if (p1 < CAP)
            __builtin_nontemporal_store(e0 + 1, &bucket[(size_t)q.z * CAP + p1]);
    } else {
        int d = nbrs[2 * e0];
        int p0 = atomicAdd(&deg[d], 1);
        if (p0 < CAP)
            __builtin_nontemporal_store(e0, &bucket[(size_t)d * CAP + p0]);
    }
}

// ---------------- gather-sum (no atomics), bf16 output ----------------
// 24 threads per node; thread covers a float4 of the 96 features.
// 8-deep pipelining; nt loads on the h stream (read-once).
__global__ __launch_bounds__(256) void gather_kernel(
    const float* __restrict__ h, const int* __restrict__ deg_arr,
    const int* __restrict__ bucket, unsigned short* __restrict__ msg16,
    int n_nodes)
{
    int t = blockIdx.x * 256 + threadIdx.x;
    int node = t / 24;
    if (node >= n_nodes) return;
    int f4 = (t - node * 24) * 4;
    int deg = deg_arr[node]; if (deg > CAP) deg = CAP;
    const int* brow = bucket + (size_t)node * CAP;

    f32x4 a0 = (f32x4){0.f,0.f,0.f,0.f}, a1 = a0, a2 = a0, a3 = a0;
    f32x4 a4 = a0, a5 = a0, a6 = a0, a7 = a0;
    int i = 0;
    for (; i + 8 <= deg; i += 8) {
        int4 ea = *reinterpret_cast<const int4*>(brow + i);
        int4 eb = *reinterpret_cast<const int4*>(brow + i + 4);
        const f32x4 v0 = __builtin_nontemporal_load(
            reinterpret_cast<const f32x4*>(h + (size_t)ea.x * D_H + f4));
        const f32x4 v1 = __builtin_nontemporal_load(
            reinterpret_cast<const f32x4*>(h + (size_t)ea.y * D_H + f4));
        const f32x4 v2 = __builtin_nontemporal_load(
            reinterpret_cast<const f32x4*>(h + (size_t)ea.z * D_H + f4));
        const f32x4 v3 = __builtin_nontemporal_load(
            reinterpret_cast<const f32x4*>(h + (size_t)ea.w * D_H + f4));
        const f32x4 v4 = __builtin_nontemporal_load(
            reinterpret_cast<const f32x4*>(h + (size_t)eb.x * D_H + f4));
        const f32x4 v5 = __builtin_nontemporal_load(
            reinterpret_cast<const f32x4*>(h + (size_t)eb.y * D_H + f4));
        const f32x4 v6 = __builtin_nontemporal_load(
            reinterpret_cast<const f32x4*>(h + (size_t)eb.z * D_H + f4));
        const f32x4 v7 = __builtin_nontemporal_load(
            reinterpret_cast<const f32x4*>(h + (size_t)eb.w * D_H + f4));
        a0 += v0; a1 += v1; a2 += v2; a3 += v3;
        a4 += v4; a5 += v5; a6 += v6; a7 += v7;
    }
    for (; i + 4 <= deg; i += 4) {
        int4 ea = *reinterpret_cast<const int4*>(brow + i);
        a0 += __builtin_nontemporal_load(
            reinterpret_cast<const f32x4*>(h + (size_t)ea.x * D_H + f4));
        a1 += __builtin_nontemporal_load(
            reinterpret_cast<const f32x4*>(h + (size_t)ea.y * D_H + f4));
        a2 += __builtin_nontemporal_load(
            reinterpret_cast<const f32x4*>(h + (size_t)ea.z * D_H + f4));
        a3 += __builtin_nontemporal_load(
            reinterpret_cast<const f32x4*>(h + (size_t)ea.w * D_H + f4));
    }
    for (; i < deg; ++i) {
        int e = brow[i];
        a0 += __builtin_nontemporal_load(
            reinterpret_cast<const f32x4*>(h + (size_t)e * D_H + f4));
    }
    f32x4 s = ((a0 + a1) + (a2 + a3)) + ((a4 + a5) + (a6 + a7));
    ushort4 o;
    o.x = f2b(s.x); o.y = f2b(s.y); o.z = f2b(s.z); o.w = f2b(s.w);
    *reinterpret_cast<ushort4*>(msg16 + (size_t)node * D_H + f4) = o;
}

// -------- MFMA GEMM: out = relu([r | msg] @ W^T), bf16 inputs, f32 acc ----
// All 22 per-lane global loads issued upfront, in flight under W staging.
__global__ __launch_bounds__(256) void mfma_gemm_kernel(
    const float* __restrict__ r, const unsigned short* __restrict__ msg16,
    const unsigned short* __restrict__ W16, float* __restrict__ out, int n_nodes)
{
    __shared__ unsigned short Wl[D_OUT * WPAD];   // 44544 B

    const int lane = threadIdx.x & 63;
    const int wv   = threadIdx.x >> 6;      // 0..3
    const int cl   = lane & 15;
    const int kch  = (lane >> 4) * 8;

    const int rowbase = blockIdx.x * 128 + wv * 32;

    int arow0 = rowbase + cl;       if (arow0 >= n_nodes) arow0 = n_nodes - 1;
    int arow1 = rowbase + 16 + cl;  if (arow1 >= n_nodes) arow1 = n_nodes - 1;

    const float* rb[2] = { r + (size_t)arow0 * D_R + kch,
                           r + (size_t)arow1 * D_R + kch };
    const unsigned short* mb[2] = { msg16 + (size_t)arow0 * D_H + kch,
                                    msg16 + (size_t)arow1 * D_H + kch };

    // ---- issue ALL global loads upfront ----
    f32x4 rbuf[2][8];     // [mf][2*ks + half], offset = ks*32 + half*4
    short8 mbuf[2][3];    // [mf][ks]
#pragma unroll
    for (int mf = 0; mf < 2; ++mf) {
#pragma unroll
        for (int q = 0; q < 8; ++q) {
            const int off = (q >> 1) * 32 + (q & 1) * 4;
            rbuf[mf][q] = __builtin_nontemporal_load(
                reinterpret_cast<const f32x4*>(rb[mf] + off));
        }
#pragma unroll
        for (int ks = 0; ks < 3; ++ks)
            mbuf[mf][ks] = *reinterpret_cast<const short8*>(mb[mf] + ks * 32);
    }

    // ---- stage W (bf16) -> padded LDS via 16B copies, overlapped ----
    for (int c = threadIdx.x; c < D_OUT * (D_IN / 8); c += 256) {
        int j = c / 28, p = c - j * 28;
        *reinterpret_cast<short8*>(&Wl[j * WPAD + p * 8]) =
            *reinterpret_cast<const short8*>(&W16[j * D_IN + p * 8]);
    }
    __syncthreads();

    f32x4 acc[2][6];
#pragma unroll
    for (int mf = 0; mf < 2; ++mf)
#pragma unroll
        for (int nf = 0; nf < 6; ++nf) acc[mf][nf] = (f32x4){0.f, 0.f, 0.f, 0.f};

    // ---- phase 1: k-steps 0..3 from rbuf (fp32 -> bf16 in-register) ----
#pragma unroll
    for (int ks = 0; ks < 4; ++ks) {
        const int k0 = ks * 32;
        short8 a[2];
#pragma unroll
        for (int mf = 0; mf < 2; ++mf) {
            const f32x4 u = rbuf[mf][2 * ks];
            const f32x4 v = rbuf[mf][2 * ks + 1];
            short8 tv;
            tv[0] = (short)f2b(u.x); tv[1] = (short)f2b(u.y);
            tv[2] = (short)f2b(u.z); tv[3] = (short)f2b(u.w);
            tv[4] = (short)f2b(v.x); tv[5] = (short)f2b(v.y);
            tv[6] = (short)f2b(v.z); tv[7] = (short)f2b(v.w);
            a[mf] = tv;
        }
#pragma unroll
        for (int nf = 0; nf < 6; ++nf) {
            const short8 b = *reinterpret_cast<const short8*>(
                &Wl[(nf * 16 + cl) * WPAD + k0 + kch]);
            acc[0][nf] = __builtin_amdgcn_mfma_f32_16x16x32_bf16(a[0], b, acc[0][nf], 0, 0, 0);
            acc[1][nf] = __builtin_amdgcn_mfma_f32_16x16x32_bf16(a[1], b, acc[1][nf], 0, 0, 0);
        }
    }

    // ---- phase 2: k-steps 4..6 from mbuf ----
#pragma unroll
    for (int ks = 0; ks < 3; ++ks) {
        const int k0 = ks * 32;
#pragma unroll
        for (int nf = 0; nf < 6; ++nf) {
            const short8 b = *reinterpret_cast<const short8*>(
                &Wl[(nf * 16 + cl) * WPAD + D_R + k0 + kch]);
            acc[0][nf] = __builtin_amdgcn_mfma_f32_16x16x32_bf16(mbuf[0][ks], b, acc[0][nf], 0, 0, 0);
            acc[1][nf] = __builtin_amdgcn_mfma_f32_16x16x32_bf16(mbuf[1][ks], b, acc[1][nf], 0, 0, 0);
        }
    }

    // ---- epilogue: ReLU + nontemporal store (out is write-once) ----
    const int g4 = (lane >> 4) * 4;
#pragma unroll
    for (int mf = 0; mf < 2; ++mf) {
#pragma unroll
        for (int q = 0; q < 4; ++q) {
            const int row = rowbase + mf * 16 + g4 + q;
            if (row < n_nodes) {
                float* op = out + (size_t)row * D_OUT + cl;
#pragma unroll
                for (int nf = 0; nf < 6; ++nf)
                    __builtin_nontemporal_store(fmaxf(acc[mf][nf][q], 0.f), op + nf * 16);
            }
        }
    }
}

extern "C" void kernel_launch(void* const* d_in, const int* in_sizes, int n_in,
                              void* d_out, int out_size, void* d_ws, size_t ws_size,
                              hipStream_t stream) {
    const float* r    = (const float*)d_in[0];
    const float* h    = (const float*)d_in[1];
    const int*   nbrs = (const int*)d_in[2];
    const float* W    = (const float*)d_in[3];
    float*       out  = (float*)d_out;

    const int n_nodes = in_sizes[0] / D_R;
    const int n_edges = in_sizes[2] / 2;

    // workspace layout (16B-aligned offsets)
    char* ws = (char*)d_ws;
    unsigned short* msg16 = (unsigned short*)ws;                       // n_nodes*D_H bf16
    size_t off = (size_t)n_nodes * D_H * sizeof(unsigned short);
    int* deg    = (int*)(ws + off);  off += (size_t)n_nodes * sizeof(int);
    int* bucket = (int*)(ws + off);  off += (size_t)n_nodes * CAP * sizeof(int);
    unsigned short* W16 = (unsigned short*)(ws + off);                 // NW bf16

    const int pair_blocks = ((n_edges + 1) / 2 + 255) / 256;
    const int init_blocks = (n_nodes > NW ? n_nodes : NW) / 256 + 1;

    init_kernel<<<init_blocks, 256, 0, stream>>>(deg, n_nodes, W, W16);
    build_kernel<<<pair_blocks, 256, 0, stream>>>(nbrs, deg, bucket, n_edges);

    {
        long long total = (long long)n_nodes * 24;
        int blocks = (int)((total + 255) / 256);
        gather_kernel<<<blocks, 256, 0, stream>>>(h, deg, bucket, msg16, n_nodes);
    }
    {
        dim3 grid((n_nodes + 127) / 128);
        mfma_gemm_kernel<<<grid, 256, 0, stream>>>(r, msg16, W16, out, n_nodes);
    }
}

// Round 13
// 160.884 us; speedup vs baseline: 1.0405x; 1.0405x over previous
//
#include <hip/hip_runtime.h>
#include <hip/hip_bf16.h>

#define D_R 128
#define D_H 96
#define D_IN 224   // D_R + D_H
#define D_OUT 96
#define CAP 64     // bucket slots per node (256B rows, line-aligned); P(deg>=64) ~ 1e-38
#define NW 21504   // D_OUT * D_IN
#define WPAD 232   // padded W row stride in bf16 (464B: 2-way LDS alias only)

typedef __attribute__((ext_vector_type(8))) short short8;
typedef __attribute__((ext_vector_type(4))) float f32x4;

static __device__ inline unsigned short f2b(float x) {
    __hip_bfloat16 b = __float2bfloat16(x);
    unsigned short u;
    __builtin_memcpy(&u, &b, 2);
    return u;
}

// -------- init: zero deg + convert W fp32->bf16 (one kernel, two ranges) ----
__global__ __launch_bounds__(256) void init_kernel(
    int* __restrict__ deg, int n_nodes,
    const float* __restrict__ W, unsigned short* __restrict__ W16)
{
    int i = blockIdx.x * 256 + threadIdx.x;
    if (i < n_nodes) deg[i] = 0;
    if (i < NW) W16[i] = f2b(W[i]);
}

// -------- single-pass bucket build (count+alloc+fill merged) ----------------
__global__ __launch_bounds__(256) void build_kernel(
    const int* __restrict__ nbrs, int* __restrict__ deg,
    int* __restrict__ bucket, int n_edges)
{
    int k = blockIdx.x * 256 + threadIdx.x;
    int e0 = 2 * k;
    if (e0 >= n_edges) return;
    if (e0 + 1 < n_edges) {
        int4 q = *reinterpret_cast<const int4*>(nbrs + 2 * e0);
        int p0 = atomicAdd(&deg[q.x], 1);
        if (p0 < CAP) bucket[(size_t)q.x * CAP + p0] = e0;
        int p1 = atomicAdd(&deg[q.z], 1);
        if (p1 < CAP) bucket[(size_t)q.z * CAP + p1] = e0 + 1;
    } else {
        int d = nbrs[2 * e0];
        int p0 = atomicAdd(&deg[d], 1);
        if (p0 < CAP) bucket[(size_t)d * CAP + p0] = e0;
    }
}

// ---------------- gather-sum (no atomics), bf16 output ----------------
// 24 threads per node; thread covers a float4 of the 96 features.
// 8-deep pipelining: both int4 edge-ID loads + 8 h loads in flight before
// any accumulate (median node = one burst).
__global__ __launch_bounds__(256) void gather_kernel(
    const float* __restrict__ h, const int* __restrict__ deg_arr,
    const int* __restrict__ bucket, unsigned short* __restrict__ msg16,
    int n_nodes)
{
    int t = blockIdx.x * 256 + threadIdx.x;
    int node = t / 24;
    if (node >= n_nodes) return;
    int f4 = (t - node * 24) * 4;
    int deg = deg_arr[node]; if (deg > CAP) deg = CAP;
    const int* brow = bucket + (size_t)node * CAP;

    f32x4 a0 = (f32x4){0.f,0.f,0.f,0.f}, a1 = a0, a2 = a0, a3 = a0;
    f32x4 a4 = a0, a5 = a0, a6 = a0, a7 = a0;
    int i = 0;
    for (; i + 8 <= deg; i += 8) {
        int4 ea = *reinterpret_cast<const int4*>(brow + i);
        int4 eb = *reinterpret_cast<const int4*>(brow + i + 4);
        const f32x4 v0 = __builtin_nontemporal_load(
            reinterpret_cast<const f32x4*>(h + (size_t)ea.x * D_H + f4));
        const f32x4 v1 = __builtin_nontemporal_load(
            reinterpret_cast<const f32x4*>(h + (size_t)ea.y * D_H + f4));
        const f32x4 v2 = __builtin_nontemporal_load(
            reinterpret_cast<const f32x4*>(h + (size_t)ea.z * D_H + f4));
        const f32x4 v3 = __builtin_nontemporal_load(
            reinterpret_cast<const f32x4*>(h + (size_t)ea.w * D_H + f4));
        const f32x4 v4 = __builtin_nontemporal_load(
            reinterpret_cast<const f32x4*>(h + (size_t)eb.x * D_H + f4));
        const f32x4 v5 = __builtin_nontemporal_load(
            reinterpret_cast<const f32x4*>(h + (size_t)eb.y * D_H + f4));
        const f32x4 v6 = __builtin_nontemporal_load(
            reinterpret_cast<const f32x4*>(h + (size_t)eb.z * D_H + f4));
        const f32x4 v7 = __builtin_nontemporal_load(
            reinterpret_cast<const f32x4*>(h + (size_t)eb.w * D_H + f4));
        a0 += v0; a1 += v1; a2 += v2; a3 += v3;
        a4 += v4; a5 += v5; a6 += v6; a7 += v7;
    }
    for (; i + 4 <= deg; i += 4) {
        int4 ea = *reinterpret_cast<const int4*>(brow + i);
        a0 += __builtin_nontemporal_load(
            reinterpret_cast<const f32x4*>(h + (size_t)ea.x * D_H + f4));
        a1 += __builtin_nontemporal_load(
            reinterpret_cast<const f32x4*>(h + (size_t)ea.y * D_H + f4));
        a2 += __builtin_nontemporal_load(
            reinterpret_cast<const f32x4*>(h + (size_t)ea.z * D_H + f4));
        a3 += __builtin_nontemporal_load(
            reinterpret_cast<const f32x4*>(h + (size_t)ea.w * D_H + f4));
    }
    for (; i < deg; ++i) {
        int e = brow[i];
        a0 += __builtin_nontemporal_load(
            reinterpret_cast<const f32x4*>(h + (size_t)e * D_H + f4));
    }
    f32x4 s = ((a0 + a1) + (a2 + a3)) + ((a4 + a5) + (a6 + a7));
    ushort4 o;
    o.x = f2b(s.x); o.y = f2b(s.y); o.z = f2b(s.z); o.w = f2b(s.w);
    *reinterpret_cast<ushort4*>(msg16 + (size_t)node * D_H + f4) = o;
}

// -------- MFMA GEMM: out = relu([r | msg] @ W^T), bf16 inputs, f32 acc ----
// All 22 per-lane global loads (16x r f32x4, 6x msg short8) issued upfront,
// in flight under the W LDS staging + barrier.
__global__ __launch_bounds__(256) void mfma_gemm_kernel(
    const float* __restrict__ r, const unsigned short* __restrict__ msg16,
    const unsigned short* __restrict__ W16, float* __restrict__ out, int n_nodes)
{
    __shared__ unsigned short Wl[D_OUT * WPAD];   // 44544 B

    const int lane = threadIdx.x & 63;
    const int wv   = threadIdx.x >> 6;      // 0..3
    const int cl   = lane & 15;
    const int kch  = (lane >> 4) * 8;

    const int rowbase = blockIdx.x * 128 + wv * 32;

    int arow0 = rowbase + cl;       if (arow0 >= n_nodes) arow0 = n_nodes - 1;
    int arow1 = rowbase + 16 + cl;  if (arow1 >= n_nodes) arow1 = n_nodes - 1;

    const float* rb[2] = { r + (size_t)arow0 * D_R + kch,
                           r + (size_t)arow1 * D_R + kch };
    const unsigned short* mb[2] = { msg16 + (size_t)arow0 * D_H + kch,
                                    msg16 + (size_t)arow1 * D_H + kch };

    // ---- issue ALL global loads upfront ----
    f32x4 rbuf[2][8];     // [mf][2*ks + half], offset = ks*32 + half*4
    short8 mbuf[2][3];    // [mf][ks]
#pragma unroll
    for (int mf = 0; mf < 2; ++mf) {
#pragma unroll
        for (int q = 0; q < 8; ++q) {
            const int off = (q >> 1) * 32 + (q & 1) * 4;
            rbuf[mf][q] = __builtin_nontemporal_load(
                reinterpret_cast<const f32x4*>(rb[mf] + off));
        }
#pragma unroll
        for (int ks = 0; ks < 3; ++ks)
            mbuf[mf][ks] = *reinterpret_cast<const short8*>(mb[mf] + ks * 32);
    }

    // ---- stage W (bf16) -> padded LDS via 16B copies, overlapped ----
    for (int c = threadIdx.x; c < D_OUT * (D_IN / 8); c += 256) {
        int j = c / 28, p = c - j * 28;
        *reinterpret_cast<short8*>(&Wl[j * WPAD + p * 8]) =
            *reinterpret_cast<const short8*>(&W16[j * D_IN + p * 8]);
    }
    __syncthreads();

    f32x4 acc[2][6];
#pragma unroll
    for (int mf = 0; mf < 2; ++mf)
#pragma unroll
        for (int nf = 0; nf < 6; ++nf) acc[mf][nf] = (f32x4){0.f, 0.f, 0.f, 0.f};

    // ---- phase 1: k-steps 0..3 from rbuf (fp32 -> bf16 in-register) ----
#pragma unroll
    for (int ks = 0; ks < 4; ++ks) {
        const int k0 = ks * 32;
        short8 a[2];
#pragma unroll
        for (int mf = 0; mf < 2; ++mf) {
            const f32x4 u = rbuf[mf][2 * ks];
            const f32x4 v = rbuf[mf][2 * ks + 1];
            short8 tv;
            tv[0] = (short)f2b(u.x); tv[1] = (short)f2b(u.y);
            tv[2] = (short)f2b(u.z); tv[3] = (short)f2b(u.w);
            tv[4] = (short)f2b(v.x); tv[5] = (short)f2b(v.y);
            tv[6] = (short)f2b(v.z); tv[7] = (short)f2b(v.w);
            a[mf] = tv;
        }
#pragma unroll
        for (int nf = 0; nf < 6; ++nf) {
            const short8 b = *reinterpret_cast<const short8*>(
                &Wl[(nf * 16 + cl) * WPAD + k0 + kch]);
            acc[0][nf] = __builtin_amdgcn_mfma_f32_16x16x32_bf16(a[0], b, acc[0][nf], 0, 0, 0);
            acc[1][nf] = __builtin_amdgcn_mfma_f32_16x16x32_bf16(a[1], b, acc[1][nf], 0, 0, 0);
        }
    }

    // ---- phase 2: k-steps 4..6 from mbuf ----
#pragma unroll
    for (int ks = 0; ks < 3; ++ks) {
        const int k0 = ks * 32;
#pragma unroll
        for (int nf = 0; nf < 6; ++nf) {
            const short8 b = *reinterpret_cast<const short8*>(
                &Wl[(nf * 16 + cl) * WPAD + D_R + k0 + kch]);
            acc[0][nf] = __builtin_amdgcn_mfma_f32_16x16x32_bf16(mbuf[0][ks], b, acc[0][nf], 0, 0, 0);
            acc[1][nf] = __builtin_amdgcn_mfma_f32_16x16x32_bf16(mbuf[1][ks], b, acc[1][nf], 0, 0, 0);
        }
    }

    // ---- epilogue: ReLU + nontemporal store ----
    const int g4 = (lane >> 4) * 4;
#pragma unroll
    for (int mf = 0; mf < 2; ++mf) {
#pragma unroll
        for (int q = 0; q < 4; ++q) {
            const int row = rowbase + mf * 16 + g4 + q;
            if (row < n_nodes) {
                float* op = out + (size_t)row * D_OUT + cl;
#pragma unroll
                for (int nf = 0; nf < 6; ++nf)
                    __builtin_nontemporal_store(fmaxf(acc[mf][nf][q], 0.f), op + nf * 16);
            }
        }
    }
}

extern "C" void kernel_launch(void* const* d_in, const int* in_sizes, int n_in,
                              void* d_out, int out_size, void* d_ws, size_t ws_size,
                              hipStream_t stream) {
    const float* r    = (const float*)d_in[0];
    const float* h    = (const float*)d_in[1];
    const int*   nbrs = (const int*)d_in[2];
    const float* W    = (const float*)d_in[3];
    float*       out  = (float*)d_out;

    const int n_nodes = in_sizes[0] / D_R;
    const int n_edges = in_sizes[2] / 2;

    // workspace layout (16B-aligned offsets)
    char* ws = (char*)d_ws;
    unsigned short* msg16 = (unsigned short*)ws;                       // n_nodes*D_H bf16
    size_t off = (size_t)n_nodes * D_H * sizeof(unsigned short);
    int* deg    = (int*)(ws + off);  off += (size_t)n_nodes * sizeof(int);
    int* bucket = (int*)(ws + off);  off += (size_t)n_nodes * CAP * sizeof(int);
    unsigned short* W16 = (unsigned short*)(ws + off);                 // NW bf16

    const int pair_blocks = ((n_edges + 1) / 2 + 255) / 256;
    const int init_blocks = (n_nodes > NW ? n_nodes : NW) / 256 + 1;

    init_kernel<<<init_blocks, 256, 0, stream>>>(deg, n_nodes, W, W16);
    build_kernel<<<pair_blocks, 256, 0, stream>>>(nbrs, deg, bucket, n_edges);

    {
        long long total = (long long)n_nodes * 24;
        int blocks = (int)((total + 255) / 256);
        gather_kernel<<<blocks, 256, 0, stream>>>(h, deg, bucket, msg16, n_nodes);
    }
    {
        dim3 grid((n_nodes + 127) / 128);
        mfma_gemm_kernel<<<grid, 256, 0, stream>>>(r, msg16, W16, out, n_nodes);
    }
}